// Round 7
// baseline (207.729 us; speedup 1.0000x reference)
//
#include <hip/hip_runtime.h>
#include <math.h>

typedef unsigned short u16;
typedef __attribute__((ext_vector_type(8))) _Float16 half8;    // 8 fp16
typedef __attribute__((ext_vector_type(4))) float    f32x4;

#define BATCH 4
#define NPB   4096      // pixels per batch (H*W)
#define BN    16384     // BATCH * NPB
#define CC    256       // input channels
#define D     128       // output channels (C/2)
#define LOG2E 1.44269504088896f

#if __has_builtin(__builtin_amdgcn_exp2f)
#define EXP2(x) __builtin_amdgcn_exp2f(x)
#else
#define EXP2(x) exp2f(x)
#endif

// 16-lane (DPP row) reductions on the VALU pipe — no LDS crossbar.
template<int CTRL>
__device__ __forceinline__ float dpp_mov(float x) {
    return __builtin_bit_cast(float, __builtin_amdgcn_update_dpp(
        __builtin_bit_cast(int, x), __builtin_bit_cast(int, x),
        CTRL, 0xf, 0xf, false));
}
__device__ __forceinline__ float dpp_row_max(float x) {
    x = fmaxf(x, dpp_mov<0x128>(x));   // row_ror:8
    x = fmaxf(x, dpp_mov<0x124>(x));   // row_ror:4
    x = fmaxf(x, dpp_mov<0x122>(x));   // row_ror:2
    x = fmaxf(x, dpp_mov<0x121>(x));   // row_ror:1
    return x;
}
__device__ __forceinline__ float dpp_row_sum(float x) {
    x += dpp_mov<0x128>(x);
    x += dpp_mov<0x124>(x);
    x += dpp_mov<0x122>(x);
    x += dpp_mov<0x121>(x);
    return x;
}

// ---------------------------------------------------------------------------
// Projection via fp16 MFMA. Grid (128, 4): 128 pixels x one matrix per block.
// x-tile staged ONCE (coalesced flat loads) -> fp16 LDS; one sync; 128 MFMAs
// per wave. W-fragments in registers.
//   by=0: K*log2e -> fp16 [n][128]   by=1: Q -> fp16 [n][128]
//   by=2: V -> fp16 [b][c][4096]     by=3: shortcut -> fp32 [n][128]
// by 0/1/3 use swapped operands (D[c][m]) for packed stores.
// ---------------------------------------------------------------------------
#define APJ 264         // As row pitch in u16 (528 B = 33*16 -> 4-bank row shift)

__global__ __launch_bounds__(256, 2) void proj_kernel(
    const float* __restrict__ x,
    const float* __restrict__ Wk, const float* __restrict__ bk,
    const float* __restrict__ Wq, const float* __restrict__ bq,
    const float* __restrict__ Wv, const float* __restrict__ bv,
    const float* __restrict__ Ws, const float* __restrict__ bs,
    u16* __restrict__ Kh, u16* __restrict__ Qh,
    u16* __restrict__ Vt, float* __restrict__ Sc)
{
    __shared__ __align__(16) u16 As[128][APJ];   // 66 KB

    const int tid = threadIdx.x;
    const int wv  = tid >> 6;
    const int l   = tid & 63;
    const int l15 = l & 15;
    const int l4  = l >> 4;
    const int by  = blockIdx.y;
    const int gm0 = blockIdx.x * 128;
    const int c0  = wv * 32;

    const float* W    = (by == 0) ? Wk : (by == 1) ? Wq : (by == 2) ? Wv : Ws;
    const float* bias = (by == 0) ? bk : (by == 1) ? bq : (by == 2) ? bv : bs;

    // ---- preload W fragments: Bf[ct][kc], lane -> W[k][c0+ct*16+l15]
    half8 Bf[2][8];
#pragma unroll
    for (int ct = 0; ct < 2; ++ct) {
        const int c = c0 + ct * 16 + l15;
#pragma unroll
        for (int kc = 0; kc < 8; ++kc) {
            const int kb = kc * 32 + l4 * 8;
#pragma unroll
            for (int j = 0; j < 8; ++j)
                Bf[ct][kc][j] = (_Float16)W[(size_t)(kb + j) * D + c];
        }
    }

    // ---- stage the whole x-tile once (fully coalesced: thread t -> float4 t)
    {
        const float4* xg = (const float4*)(x + (size_t)gm0 * CC);
#pragma unroll 8
        for (int i = 0; i < 32; ++i) {
            const int f = i * 256 + tid;           // flat float4 index
            const float4 v = xg[f];
            const int row = f >> 6, col4 = f & 63;
            _Float16 h[4] = {(_Float16)v.x, (_Float16)v.y,
                             (_Float16)v.z, (_Float16)v.w};
            *(uint2*)&As[row][col4 * 4] = *(const uint2*)h;
        }
    }
    __syncthreads();

    f32x4 acc[8][2];
#pragma unroll
    for (int mt = 0; mt < 8; ++mt) {
        acc[mt][0] = (f32x4){0.f, 0.f, 0.f, 0.f};
        acc[mt][1] = (f32x4){0.f, 0.f, 0.f, 0.f};
    }

    if (by == 2) {
        for (int kc = 0; kc < 8; ++kc) {
#pragma unroll
            for (int mt = 0; mt < 8; ++mt) {
                const half8 a = *(const half8*)&As[mt * 16 + l15][kc * 32 + l4 * 8];
                acc[mt][0] = __builtin_amdgcn_mfma_f32_16x16x32_f16(a, Bf[0][kc], acc[mt][0], 0, 0, 0);
                acc[mt][1] = __builtin_amdgcn_mfma_f32_16x16x32_f16(a, Bf[1][kc], acc[mt][1], 0, 0, 0);
            }
        }
        // V: D[m][c]; fp16 transposed [batch][c][m], pack 4 consecutive m
        const float bb[2] = {bias[c0 + l15], bias[c0 + 16 + l15]};
        const int batch = gm0 >> 12;
        const int mb0   = (gm0 & 4095) + l4 * 4;
        u16* vb = Vt + (size_t)batch * (D * NPB);
#pragma unroll
        for (int mt = 0; mt < 8; ++mt) {
#pragma unroll
            for (int ct = 0; ct < 2; ++ct) {
                const int c = c0 + ct * 16 + l15;
                _Float16 t4[4];
#pragma unroll
                for (int r = 0; r < 4; ++r)
                    t4[r] = (_Float16)(acc[mt][ct][r] + bb[ct]);
                *(uint2*)&vb[(size_t)c * NPB + mb0 + mt * 16] = *(const uint2*)t4;
            }
        }
    } else {
        for (int kc = 0; kc < 8; ++kc) {
#pragma unroll
            for (int mt = 0; mt < 8; ++mt) {
                const half8 a = *(const half8*)&As[mt * 16 + l15][kc * 32 + l4 * 8];
                acc[mt][0] = __builtin_amdgcn_mfma_f32_16x16x32_f16(Bf[0][kc], a, acc[mt][0], 0, 0, 0);
                acc[mt][1] = __builtin_amdgcn_mfma_f32_16x16x32_f16(Bf[1][kc], a, acc[mt][1], 0, 0, 0);
            }
        }
        // swapped: D[c][m] — lane holds c = c0+ct*16+l4*4+r, m = gm0+mt*16+l15
        float bb2[2][4];
#pragma unroll
        for (int ct = 0; ct < 2; ++ct)
#pragma unroll
            for (int r = 0; r < 4; ++r)
                bb2[ct][r] = bias[c0 + ct * 16 + l4 * 4 + r];

        if (by == 3) {
#pragma unroll
            for (int mt = 0; mt < 8; ++mt) {
                const int m = gm0 + mt * 16 + l15;
#pragma unroll
                for (int ct = 0; ct < 2; ++ct) {
                    float4 v;
                    v.x = acc[mt][ct][0] + bb2[ct][0];
                    v.y = acc[mt][ct][1] + bb2[ct][1];
                    v.z = acc[mt][ct][2] + bb2[ct][2];
                    v.w = acc[mt][ct][3] + bb2[ct][3];
                    *(float4*)&Sc[(size_t)m * D + c0 + ct * 16 + l4 * 4] = v;
                }
            }
        } else {
            u16* O = (by == 0) ? Kh : Qh;
            const float scale = (by == 0) ? LOG2E : 1.0f;   // K in log2 domain
#pragma unroll
            for (int mt = 0; mt < 8; ++mt) {
                const int m = gm0 + mt * 16 + l15;
#pragma unroll
                for (int ct = 0; ct < 2; ++ct) {
                    _Float16 t4[4];
#pragma unroll
                    for (int r = 0; r < 4; ++r)
                        t4[r] = (_Float16)((acc[mt][ct][r] + bb2[ct][r]) * scale);
                    *(uint2*)&O[(size_t)m * D + c0 + ct * 16 + l4 * 4] =
                        *(const uint2*)t4;
                }
            }
        }
    }
}

// ---------------------------------------------------------------------------
// Flash attention. K pre-scaled by log2e -> softmax in exp2 domain (raw
// v_exp_f32). Running max with DPP reductions + skip-rescale branch.
// K/Q/P/V all fp16. 512 blocks x 32 n-rows; 4 waves = 2 n-grp x 2 m-half.
// ---------------------------------------------------------------------------
#define TM 32
#define QP 136          // Qs/Ks row pitch (u16)
#define VP 40           // Vs/Ps row pitch (u16)

__global__ __launch_bounds__(256) void attn_kernel(
    const u16* __restrict__ Kh, const u16* __restrict__ Qh,
    const u16* __restrict__ Vt, const float* __restrict__ Sc,
    float* __restrict__ out)
{
    __shared__ __align__(16) unsigned char smem[51712];
    u16 (*Ks)[QP]     = (u16(*)[QP])(smem);                 // 32 x 136 (fp16)
    u16 (*Qs)[TM][QP] = (u16(*)[TM][QP])(smem + 8704);      // 2 x 32 x 136 (fp16)
    u16 (*Vs)[D][VP]  = (u16(*)[D][VP])(smem + 26112);      // 2 x 128 x 40 (fp16)
    u16 (*Ps)[16][VP] = (u16(*)[16][VP])(smem + 46592);     // 4 x 16 x 40 (fp16)

    const int tid = threadIdx.x;
    const int wv  = tid >> 6;
    const int l   = tid & 63;
    const int l15 = l & 15;
    const int l4  = l >> 4;
    const int batch = blockIdx.x & 3;
    const int tile  = blockIdx.x >> 2;
    const int gr0   = batch * NPB + tile * 32;

    const int n16 = wv & 1;                 // n-group
    const int mh  = wv >> 1;                // m-half

    // ---- stage K tile (32 x 128 fp16, already log2e-scaled)
    {
        const int row = tid >> 3, ch = tid & 7;
        const uint4* src = (const uint4*)(Kh + (size_t)(gr0 + row) * D + ch * 16);
        *(uint4*)&Ks[row][ch * 16]     = src[0];
        *(uint4*)&Ks[row][ch * 16 + 8] = src[1];
    }
    __syncthreads();

    half8 kf[4];
#pragma unroll
    for (int kc = 0; kc < 4; ++kc)
        kf[kc] = *(const half8*)&Ks[n16 * 16 + l15][kc * 32 + l4 * 8];

    f32x4 Oc[8];
#pragma unroll
    for (int ct = 0; ct < 8; ++ct) Oc[ct] = (f32x4){0.f, 0.f, 0.f, 0.f};
    float mold[4], lsum[4];
#pragma unroll
    for (int r = 0; r < 4; ++r) { mold[r] = -1e30f; lsum[r] = 0.f; }

    const u16* qsrc = Qh + (size_t)(batch * NPB + wv * 2048) * D;   // wv<2 only
    const u16* vsrc = Vt + (size_t)batch * NPB * D;                 // c-major

    for (int it = 0; it < 64; ++it) {
        __syncthreads();
        const int m0 = it * TM;
        if (wv < 2) {
            const u16* s = qsrc + (size_t)m0 * D + l15 * 8;
#pragma unroll
            for (int j = 0; j < 8; ++j) {
                const int row = j * 4 + l4;
                const uint4 v = *(const uint4*)(s + (size_t)row * D);
                *(uint4*)&Qs[wv][row][l15 * 8] = v;
            }
        } else {
            const int h = wv - 2;
            const u16* s = vsrc + (size_t)(h * 2048 + m0) + (l & 3) * 8;
#pragma unroll
            for (int j = 0; j < 8; ++j) {
                const int cc = j * 16 + (l >> 2);
                const uint4 v = *(const uint4*)(s + (size_t)cc * NPB);
                *(uint4*)&Vs[h][cc][(l & 3) * 8] = v;
            }
        }
        __syncthreads();

        // ---- S' = (K*log2e) @ Q^T (fp16 MFMA, log2-domain scores)
        f32x4 sacc[2];
        sacc[0] = (f32x4){0.f, 0.f, 0.f, 0.f};
        sacc[1] = (f32x4){0.f, 0.f, 0.f, 0.f};
#pragma unroll
        for (int kc = 0; kc < 4; ++kc) {
#pragma unroll
            for (int mt = 0; mt < 2; ++mt) {
                const half8 qf =
                    *(const half8*)&Qs[mh][mt * 16 + l15][kc * 32 + l4 * 8];
                sacc[mt] = __builtin_amdgcn_mfma_f32_16x16x32_f16(
                    kf[kc], qf, sacc[mt], 0, 0, 0);
            }
        }

        // ---- online softmax (exp2 domain): DPP row-max + skip-rescale
#pragma unroll
        for (int r = 0; r < 4; ++r) {
            const float rmax = dpp_row_max(fmaxf(sacc[0][r], sacc[1][r]));
            if (__any(rmax > mold[r])) {
                const float mnew  = fmaxf(mold[r], rmax);
                const float alpha = EXP2(mold[r] - mnew);
                mold[r] = mnew;
                lsum[r] *= alpha;
#pragma unroll
                for (int ct = 0; ct < 8; ++ct) Oc[ct][r] *= alpha;
            }
            const float p0 = EXP2(sacc[0][r] - mold[r]);
            const float p1 = EXP2(sacc[1][r] - mold[r]);
            lsum[r] += p0 + p1;
            Ps[wv][l4 * 4 + r][l15]      = __builtin_bit_cast(u16, (_Float16)p0);
            Ps[wv][l4 * 4 + r][16 + l15] = __builtin_bit_cast(u16, (_Float16)p1);
        }
        asm volatile("s_waitcnt lgkmcnt(0)" ::: "memory");

        const half8 pf = *(const half8*)&Ps[wv][l15][l4 * 8];
#pragma unroll
        for (int ct = 0; ct < 8; ++ct) {
            const half8 vf = *(const half8*)&Vs[mh][ct * 16 + l15][l4 * 8];
            Oc[ct] = __builtin_amdgcn_mfma_f32_16x16x32_f16(pf, vf, Oc[ct], 0, 0, 0);
        }
    }

    // ---- final per-row sum across the 16 column-lanes (once, DPP)
#pragma unroll
    for (int r = 0; r < 4; ++r) lsum[r] = dpp_row_sum(lsum[r]);

    // ---- combine the two m-halves (waves wv and wv^2 share rows)
    __syncthreads();
    float (*Obuf)[16][D] = (float(*)[16][D])(smem);         // aliases Ks/Qs
    float* cmbM = (float*)(smem + 26112);                   // aliases Vs
    float* cmbL = (float*)(smem + 26368);

    if (l15 == 0) {
#pragma unroll
        for (int r = 0; r < 4; ++r) {
            cmbM[wv * 16 + l4 * 4 + r] = mold[r];
            cmbL[wv * 16 + l4 * 4 + r] = lsum[r];
        }
    }
    if (mh == 1) {
#pragma unroll
        for (int ct = 0; ct < 8; ++ct)
#pragma unroll
            for (int r = 0; r < 4; ++r)
                Obuf[n16][l4 * 4 + r][ct * 16 + l15] = Oc[ct][r];
    }
    __syncthreads();

    if (mh == 0) {
        float f0[4], f1[4], invL[4];
#pragma unroll
        for (int r = 0; r < 4; ++r) {
            const int row = l4 * 4 + r;
            const float M1 = cmbM[(wv + 2) * 16 + row];
            const float L1 = cmbL[(wv + 2) * 16 + row];
            const float M  = fmaxf(mold[r], M1);
            const float a0 = EXP2(mold[r] - M);
            const float a1 = EXP2(M1 - M);
            f0[r] = a0; f1[r] = a1;
            invL[r] = 1.f / (lsum[r] * a0 + L1 * a1);
        }
#pragma unroll
        for (int ct = 0; ct < 8; ++ct) {
#pragma unroll
            for (int r = 0; r < 4; ++r) {
                const int row  = l4 * 4 + r;
                const int c    = ct * 16 + l15;
                const int grow = gr0 + n16 * 16 + row;
                const float val =
                    (Oc[ct][r] * f0[r] + Obuf[n16][row][c] * f1[r]) * invL[r]
                    + Sc[(size_t)grow * D + c];
                out[(size_t)grow * D + c] = val;
            }
        }
    }
}

extern "C" void kernel_launch(void* const* d_in, const int* in_sizes, int n_in,
                              void* d_out, int out_size, void* d_ws, size_t ws_size,
                              hipStream_t stream) {
    const float* x  = (const float*)d_in[0];
    const float* Wk = (const float*)d_in[1];
    const float* bk = (const float*)d_in[2];
    const float* Wq = (const float*)d_in[3];
    const float* bq = (const float*)d_in[4];
    const float* Wv = (const float*)d_in[5];
    const float* bv = (const float*)d_in[6];
    const float* Ws = (const float*)d_in[7];
    const float* bs = (const float*)d_in[8];
    float* out = (float*)d_out;

    u16*   Kh = (u16*)d_ws;                       // 4 MB fp16 (log2e-scaled)
    u16*   Qh = Kh + (size_t)BN * D;              // 4 MB fp16
    u16*   Vt = Qh + (size_t)BN * D;              // 4 MB fp16, [b][c][m]
    float* Sc = (float*)(Vt + (size_t)BN * D);    // 8 MB fp32

    proj_kernel<<<dim3(128, 4), 256, 0, stream>>>(x, Wk, bk, Wq, bq, Wv, bv,
                                                  Ws, bs, Kh, Qh, Vt, Sc);
    attn_kernel<<<512, 256, 0, stream>>>(Kh, Qh, Vt, Sc, out);
}